// Round 4
// baseline (396.040 us; speedup 1.0000x reference)
//
#include <hip/hip_runtime.h>

typedef __attribute__((ext_vector_type(8))) short bf16x8;
typedef __attribute__((ext_vector_type(4))) float f32x4;

#define LPAD 2432
#define LKV  2382
#define NSEQ 2304
#define CDIM 512

__device__ __forceinline__ unsigned short f2bf(float f) {
  unsigned int u = __builtin_bit_cast(unsigned int, f);
  u += 0x7fffu + ((u >> 16) & 1u);
  return (unsigned short)(u >> 16);
}
__device__ __forceinline__ float bf2f(unsigned short s) {
  unsigned int u = ((unsigned int)s) << 16;
  return __builtin_bit_cast(float, u);
}
__device__ __forceinline__ f32x4 MFMA(bf16x8 a, bf16x8 b, f32x4 c) {
  return __builtin_amdgcn_mfma_f32_16x16x32_bf16(a, b, c, 0, 0, 0);
}

// ---------------- weight transpose + bf16 convert ----------------
__global__ void k_prep(const float* __restrict__ Wq, const float* __restrict__ Wkv,
                       const float* __restrict__ Wctx, const float* __restrict__ Wout,
                       unsigned short* __restrict__ WqT, unsigned short* __restrict__ WkvT,
                       unsigned short* __restrict__ WctxT, unsigned short* __restrict__ WoutT) {
  int idx = blockIdx.x * 256 + threadIdx.x;
  if (idx < 262144) {
    int n = idx >> 9, k = idx & 511;
    WqT[idx] = f2bf(Wq[k * 512 + n]);
  } else if ((idx -= 262144) < 65536) {
    int n = idx >> 9, k = idx & 511;
    WkvT[idx] = f2bf(Wkv[k * 128 + n]);
  } else if ((idx -= 65536) < 98304) {
    int n = idx / 768, k = idx - n * 768;
    WctxT[idx] = f2bf(Wctx[k * 128 + n]);
  } else {
    idx -= 98304;
    int n = idx >> 9, k = idx & 511;
    WoutT[idx] = f2bf(Wout[k * 512 + n]);
  }
}

// ---------------- LN over C of x (B,C,N) -> xn bf16 (B*N, C) ----------------
__global__ void k_ln1(const float* __restrict__ x, const float* __restrict__ g,
                      unsigned short* __restrict__ xn) {
  int b = blockIdx.y;
  int i0 = blockIdx.x * 32;
  int t = threadIdx.x;
  int ii = t & 31, ci = t >> 5;
  const float* xb = x + (size_t)b * CDIM * NSEQ;
  float s = 0.f, s2 = 0.f;
  for (int c = ci; c < CDIM; c += 8) {
    float v = xb[(size_t)c * NSEQ + i0 + ii];
    s += v; s2 += v * v;
  }
  __shared__ float ls[8][32], ls2[8][32];
  __shared__ float lmu[32], lrs[32];
  ls[ci][ii] = s; ls2[ci][ii] = s2;
  __syncthreads();
  if (t < 32) {
    float a = 0.f, a2 = 0.f;
    for (int q = 0; q < 8; q++) { a += ls[q][t]; a2 += ls2[q][t]; }
    float mu = a * (1.0f / 512.0f);
    float var = a2 * (1.0f / 512.0f) - mu * mu;
    lmu[t] = mu; lrs[t] = rsqrtf(var + 1e-5f);
  }
  __syncthreads();
  float mu = lmu[ii], rs = lrs[ii];
  unsigned short* xrow = xn + (size_t)(b * NSEQ + i0 + ii) * CDIM;
  for (int c = ci; c < CDIM; c += 8) {
    float v = xb[(size_t)c * NSEQ + i0 + ii];
    xrow[c] = f2bf((v - mu) * rs * g[c]);
  }
}

// ---------------- context LN + projection; null row + zero pads ----------
__global__ void k_ctx(const float* __restrict__ ctx, const float* __restrict__ g,
                      const float* __restrict__ be, const unsigned short* __restrict__ WctxT,
                      const float* __restrict__ bctx, const float* __restrict__ null_kv,
                      unsigned short* __restrict__ kb, unsigned short* __restrict__ vt) {
  int b = blockIdx.y, j = blockIdx.x;
  int t = threadIdx.x;
  if (j == 77) {
    if (t < 64) kb[((size_t)b * LPAD + 77) * 64 + t] = f2bf(null_kv[t]);
    else vt[((size_t)b * 64 + (t - 64)) * LPAD + 77] = f2bf(null_kv[64 + (t - 64)]);
    return;
  }
  if (j > 77) {
    int jj = LKV + (j - 78);
    if (t < 64) kb[((size_t)b * LPAD + jj) * 64 + t] = 0;
    else vt[((size_t)b * 64 + (t - 64)) * LPAD + jj] = 0;
    return;
  }
  __shared__ float row[768];
  __shared__ float red[4];
  const float* src = ctx + (size_t)(b * 77 + j) * 768;
  float s = 0.f, s2 = 0.f;
  for (int k = t; k < 768; k += 128) {
    float v = src[k];
    row[k] = v; s += v; s2 += v * v;
  }
  for (int o = 32; o; o >>= 1) { s += __shfl_xor(s, o); s2 += __shfl_xor(s2, o); }
  if ((t & 63) == 0) { red[(t >> 6) * 2] = s; red[(t >> 6) * 2 + 1] = s2; }
  __syncthreads();
  float S = red[0] + red[2], S2 = red[1] + red[3];
  float mu = S * (1.0f / 768.0f);
  float rs = rsqrtf(S2 * (1.0f / 768.0f) - mu * mu + 1e-5f);
  __syncthreads();
  for (int k = t; k < 768; k += 128) row[k] = (row[k] - mu) * rs * g[k] + be[k];
  __syncthreads();
  const uint4* w4 = reinterpret_cast<const uint4*>(WctxT + (size_t)t * 768);
  float acc = 0.f;
  for (int k8 = 0; k8 < 96; k8++) {
    union { uint4 u; unsigned short s[8]; } wv;
    wv.u = w4[k8];
#pragma unroll
    for (int e = 0; e < 8; e++) acc += row[k8 * 8 + e] * bf2f(wv.s[e]);
  }
  acc += bctx[t];
  if (t < 64) kb[((size_t)b * LPAD + j) * 64 + t] = f2bf(acc);
  else vt[((size_t)b * 64 + (t - 64)) * LPAD + j] = f2bf(acc);
}

// ---------------- MFMA GEMM ----------------
template <int MODE>
__global__ __launch_bounds__(256, 1) void k_gemm(
    const unsigned short* __restrict__ A, const unsigned short* __restrict__ BT0,
    const unsigned short* __restrict__ BT1, unsigned short* __restrict__ out_q,
    unsigned short* __restrict__ out_k, unsigned short* __restrict__ out_vt,
    float* __restrict__ out_proj) {
  int m0 = blockIdx.x * 128, n0 = blockIdx.y * 128;
  int t = threadIdx.x;
  int lane = t & 63, w = t >> 6;
  int wm = w >> 1, wn = w & 1;
  int G = lane >> 4, li = lane & 15;
  __shared__ unsigned short Al[128][72];
  __shared__ unsigned short Bl[128][72];
  const unsigned short* BT = (MODE == 0 && n0 >= 512) ? BT1 : BT0;
  int bn0 = (MODE == 0 && n0 >= 512) ? n0 - 512 : n0;
  f32x4 zero = {0.f, 0.f, 0.f, 0.f};
  f32x4 acc[4][4];
#pragma unroll
  for (int a = 0; a < 4; a++)
#pragma unroll
    for (int c = 0; c < 4; c++) acc[a][c] = zero;
  int sr = t >> 1, sc = (t & 1) * 32;
  for (int k0 = 0; k0 < 512; k0 += 64) {
    const uint4* sA = reinterpret_cast<const uint4*>(A + (size_t)(m0 + sr) * 512 + k0 + sc);
    const uint4* sB = reinterpret_cast<const uint4*>(BT + (size_t)(bn0 + sr) * 512 + k0 + sc);
    uint4 a0 = sA[0], a1 = sA[1], a2 = sA[2], a3 = sA[3];
    uint4 b0 = sB[0], b1 = sB[1], b2 = sB[2], b3 = sB[3];
    uint4* dA = reinterpret_cast<uint4*>(&Al[sr][sc]);
    uint4* dB = reinterpret_cast<uint4*>(&Bl[sr][sc]);
    dA[0] = a0; dA[1] = a1; dA[2] = a2; dA[3] = a3;
    dB[0] = b0; dB[1] = b1; dB[2] = b2; dB[3] = b3;
    __syncthreads();
#pragma unroll
    for (int ks = 0; ks < 2; ks++) {
      bf16x8 af[4], bfr[4];
#pragma unroll
      for (int f = 0; f < 4; f++) {
        af[f] = *reinterpret_cast<const bf16x8*>(&Al[wm * 64 + f * 16 + li][ks * 32 + G * 8]);
        bfr[f] = *reinterpret_cast<const bf16x8*>(&Bl[wn * 64 + f * 16 + li][ks * 32 + G * 8]);
      }
#pragma unroll
      for (int fm = 0; fm < 4; fm++)
#pragma unroll
        for (int fn = 0; fn < 4; fn++)
          acc[fm][fn] = MFMA(af[fm], bfr[fn], acc[fm][fn]);
    }
    __syncthreads();
  }
#pragma unroll
  for (int fm = 0; fm < 4; fm++)
#pragma unroll
    for (int fn = 0; fn < 4; fn++)
#pragma unroll
      for (int r = 0; r < 4; r++) {
        int row = m0 + wm * 64 + fm * 16 + G * 4 + r;
        int col = n0 + wn * 64 + fn * 16 + li;
        float v = acc[fm][fn][r];
        if (MODE == 0) {
          int b = row / NSEQ, i = row - b * NSEQ;
          if (col < 512) out_q[(size_t)row * 512 + col] = f2bf(v * 0.125f);
          else if (col < 576) out_k[((size_t)b * LPAD + 78 + i) * 64 + (col - 512)] = f2bf(v);
          else out_vt[((size_t)b * 64 + (col - 576)) * LPAD + (78 + i)] = f2bf(v);
        } else {
          out_proj[(size_t)row * 512 + col] = v;
        }
      }
}

// ---------------- flash attention: O^T layout (stats lane-local), KV-split ----
// OT[fd][fi]: C/D row = d = fd*16+G*4+r, col = i = fi*16+li. m/l per lane (li).
__device__ __forceinline__ void merge_slotT(float (*Osh)[64][34], float (*msh)[2][16],
                                            float (*lsh)[2][16], int s, f32x4 OT[4][2],
                                            float* m_, float* l_, int G, int li) {
#pragma unroll
  for (int fi = 0; fi < 2; fi++) {
    float mo = msh[s][fi][li];
    float lo = lsh[s][fi][li];
    float nm = fmaxf(m_[fi], mo);
    float ss = __expf(m_[fi] - nm);
    float so = __expf(mo - nm);
    l_[fi] = ss * l_[fi] + so * lo;
    m_[fi] = nm;
#pragma unroll
    for (int fd = 0; fd < 4; fd++)
#pragma unroll
      for (int r = 0; r < 4; r++)
        OT[fd][fi][r] = ss * OT[fd][fi][r] + so * Osh[s][fd * 16 + G * 4 + r][fi * 16 + li];
  }
}

__device__ __forceinline__ void write_slotT(float (*Osh)[64][34], float (*msh)[2][16],
                                            float (*lsh)[2][16], int s, f32x4 OT[4][2],
                                            const float* m_, const float* l_, int G, int li) {
  if (G == 0) {
    msh[s][0][li] = m_[0]; lsh[s][0][li] = l_[0];
    msh[s][1][li] = m_[1]; lsh[s][1][li] = l_[1];
  }
#pragma unroll
  for (int fd = 0; fd < 4; fd++)
#pragma unroll
    for (int fi = 0; fi < 2; fi++)
#pragma unroll
      for (int r = 0; r < 4; r++)
        Osh[s][fd * 16 + G * 4 + r][fi * 16 + li] = OT[fd][fi][r];
}

__global__ __launch_bounds__(256, 4) void k_attn(
    const unsigned short* __restrict__ q, const unsigned short* __restrict__ kbuf,
    const unsigned short* __restrict__ vt, unsigned short* __restrict__ aout) {
  int it = blockIdx.x, h = blockIdx.y, b = blockIdx.z;
  int i0 = it * 32;
  int t = threadIdx.x;
  int w = t >> 6, lane = t & 63;
  int G = lane >> 4, li = lane & 15;

  __shared__ float Osh[2][64][34];
  __shared__ float msh[2][2][16];
  __shared__ float lsh[2][2][16];

  bf16x8 qf[2][2];
#pragma unroll
  for (int fi = 0; fi < 2; fi++)
#pragma unroll
    for (int ks = 0; ks < 2; ks++)
      qf[fi][ks] = *reinterpret_cast<const bf16x8*>(
          q + (size_t)(b * NSEQ + i0 + fi * 16 + li) * CDIM + h * 64 + ks * 32 + G * 8);

  f32x4 zero = {0.f, 0.f, 0.f, 0.f};
  f32x4 OT[4][2];  // [fd][fi]
#pragma unroll
  for (int fd = 0; fd < 4; fd++)
#pragma unroll
    for (int fi = 0; fi < 2; fi++) OT[fd][fi] = zero;
  float m_[2] = {-1e30f, -1e30f};
  float l_[2] = {0.f, 0.f};

  const unsigned short* kbase = kbuf + (size_t)b * LPAD * 64;
  const unsigned short* vbase = vt + (size_t)b * 64 * LPAD;

  for (int jt = w; jt < 38; jt += 4) {
    int j0 = jt * 64;
    f32x4 S[4][2];
#pragma unroll
    for (int fj = 0; fj < 4; fj++) { S[fj][0] = zero; S[fj][1] = zero; }
#pragma unroll
    for (int ks = 0; ks < 2; ks++) {
      bf16x8 kf[4];
#pragma unroll
      for (int fj = 0; fj < 4; fj++)
        kf[fj] = *reinterpret_cast<const bf16x8*>(
            kbase + (size_t)(j0 + fj * 16 + li) * 64 + ks * 32 + G * 8);
#pragma unroll
      for (int fj = 0; fj < 4; fj++)
#pragma unroll
        for (int fi = 0; fi < 2; fi++)
          S[fj][fi] = MFMA(kf[fj], qf[fi][ks], S[fj][fi]);
    }
    if (j0 + 64 > LKV) {
#pragma unroll
      for (int fj = 0; fj < 4; fj++)
#pragma unroll
        for (int r = 0; r < 4; r++) {
          int jg = j0 + fj * 16 + G * 4 + r;
          if (jg >= LKV) { S[fj][0][r] = -1e30f; S[fj][1][r] = -1e30f; }
        }
    }
    // softmax (stats per lane li = q-row), immediate bf16 pack
    bf16x8 pf[2][2];
#pragma unroll
    for (int fi = 0; fi < 2; fi++) {
      float tm = -1e30f;
#pragma unroll
      for (int fj = 0; fj < 4; fj++)
#pragma unroll
        for (int r = 0; r < 4; r++) tm = fmaxf(tm, S[fj][fi][r]);
      tm = fmaxf(tm, __shfl_xor(tm, 16));
      tm = fmaxf(tm, __shfl_xor(tm, 32));
      float mn = fmaxf(m_[fi], tm);
      float alpha = __expf(m_[fi] - mn);
      float e[4][4];
      float ts = 0.f;
#pragma unroll
      for (int fj = 0; fj < 4; fj++)
#pragma unroll
        for (int r = 0; r < 4; r++) {
          float ev = __expf(S[fj][fi][r] - mn);
          e[fj][r] = ev;
          ts += ev;
        }
      ts += __shfl_xor(ts, 16);
      ts += __shfl_xor(ts, 32);
      l_[fi] = l_[fi] * alpha + ts;
      m_[fi] = mn;
#pragma unroll
      for (int ks = 0; ks < 2; ks++) {
        union { unsigned short s[8]; bf16x8 v; } u;
#pragma unroll
        for (int s8 = 0; s8 < 8; s8++) u.s[s8] = f2bf(e[2 * ks + (s8 >> 2)][s8 & 3]);
        pf[fi][ks] = u.v;
      }
      // per-lane scalar rescale of O^T (no shuffles!)
#pragma unroll
      for (int fd = 0; fd < 4; fd++)
#pragma unroll
        for (int r = 0; r < 4; r++) OT[fd][fi][r] *= alpha;
    }
#pragma unroll
    for (int ks = 0; ks < 2; ks++) {
#pragma unroll
      for (int fd = 0; fd < 4; fd++) {
        const unsigned short* vrow =
            vbase + (size_t)(fd * 16 + li) * LPAD + j0 + ks * 32 + G * 4;
        union { unsigned short s[8]; bf16x8 v; } uv;
        *reinterpret_cast<uint2*>(&uv.s[0]) = *reinterpret_cast<const uint2*>(vrow);
        *reinterpret_cast<uint2*>(&uv.s[4]) = *reinterpret_cast<const uint2*>(vrow + 16);
#pragma unroll
        for (int fi = 0; fi < 2; fi++) OT[fd][fi] = MFMA(uv.v, pf[fi][ks], OT[fd][fi]);
      }
    }
  }

  // tree merge: (0<-2, 1<-3) then (0<-1)
  if (w >= 2) write_slotT(Osh, msh, lsh, w - 2, OT, m_, l_, G, li);
  __syncthreads();
  if (w < 2) merge_slotT(Osh, msh, lsh, w, OT, m_, l_, G, li);
  __syncthreads();
  if (w == 1) write_slotT(Osh, msh, lsh, 0, OT, m_, l_, G, li);
  __syncthreads();
  if (w == 0) {
    merge_slotT(Osh, msh, lsh, 0, OT, m_, l_, G, li);
#pragma unroll
    for (int fi = 0; fi < 2; fi++) {
      float inv = 1.0f / l_[fi];
#pragma unroll
      for (int fd = 0; fd < 4; fd++) {
        union { unsigned short us[4]; uint2 u2; } pk;
#pragma unroll
        for (int r = 0; r < 4; r++) pk.us[r] = f2bf(OT[fd][fi][r] * inv);
        *reinterpret_cast<uint2*>(
            aout + (size_t)(b * NSEQ + i0 + fi * 16 + li) * CDIM + h * 64 + fd * 16 + G * 4) =
            pk.u2;
      }
    }
  }
}

// ---------------- per-row LN stats of proj (coalesced) ----------------
__global__ void k_stats(const float* __restrict__ proj, float* __restrict__ musig) {
  int w = threadIdx.x >> 6, lane = threadIdx.x & 63;
  int row = blockIdx.x * 4 + w;
  const float* pr = proj + (size_t)row * CDIM;
  const float4* p4 = reinterpret_cast<const float4*>(pr + lane * 8);
  float4 a = p4[0], bq = p4[1];
  float s = a.x + a.y + a.z + a.w + bq.x + bq.y + bq.z + bq.w;
  float s2 = a.x * a.x + a.y * a.y + a.z * a.z + a.w * a.w +
             bq.x * bq.x + bq.y * bq.y + bq.z * bq.z + bq.w * bq.w;
  for (int o = 32; o; o >>= 1) { s += __shfl_xor(s, o); s2 += __shfl_xor(s2, o); }
  if (lane == 0) {
    float mu = s * (1.0f / 512.0f);
    float var = s2 * (1.0f / 512.0f) - mu * mu;
    musig[row] = mu;
    musig[4 * NSEQ + row] = rsqrtf(var + 1e-5f);
  }
}

// ---------------- final LN + residual, LDS-transposed, fully coalesced ------
__global__ void k_final2(const float* __restrict__ proj, const float* __restrict__ musig,
                         const float* __restrict__ g, const float* __restrict__ x,
                         float* __restrict__ y) {
  int i0 = blockIdx.x * 32, c0 = blockIdx.y * 64, b = blockIdx.z;
  int t = threadIdx.x;
  __shared__ float lds[32][65];
  {
    int il = t >> 3, cB = (t & 7) * 8;
    const float4* src = reinterpret_cast<const float4*>(
        proj + (size_t)(b * NSEQ + i0 + il) * CDIM + c0 + cB);
    float4 v0 = src[0], v1 = src[1];
    *reinterpret_cast<float4*>(&lds[il][cB]) = v0;
    *reinterpret_cast<float4*>(&lds[il][cB + 4]) = v1;
  }
  __syncthreads();
  int ii = t & 31, cg = t >> 5;
  float mu = musig[b * NSEQ + i0 + ii];
  float rs = musig[4 * NSEQ + b * NSEQ + i0 + ii];
  const float* xb = x + (size_t)b * CDIM * NSEQ;
  float* yb = y + (size_t)b * CDIM * NSEQ;
#pragma unroll
  for (int cc = 0; cc < 8; cc++) {
    int cl = cg * 8 + cc;
    int c = c0 + cl;
    float v = lds[ii][cl];
    yb[(size_t)c * NSEQ + i0 + ii] = xb[(size_t)c * NSEQ + i0 + ii] + (v - mu) * rs * g[c];
  }
}

extern "C" void kernel_launch(void* const* d_in, const int* in_sizes, int n_in,
                              void* d_out, int out_size, void* d_ws, size_t ws_size,
                              hipStream_t stream) {
  const float* x       = (const float*)d_in[0];
  const float* context = (const float*)d_in[1];
  const float* ngamma  = (const float*)d_in[2];
  const float* null_kv = (const float*)d_in[3];
  const float* Wq      = (const float*)d_in[4];
  const float* Wkv     = (const float*)d_in[5];
  const float* clng    = (const float*)d_in[6];
  const float* clnb    = (const float*)d_in[7];
  const float* Wctx    = (const float*)d_in[8];
  const float* bctx    = (const float*)d_in[9];
  const float* Wout    = (const float*)d_in[10];
  const float* olng    = (const float*)d_in[11];
  float* y = (float*)d_out;
  char* ws = (char*)d_ws;

  unsigned short* xn    = (unsigned short*)(ws);              // 9437184 B
  unsigned short* qb    = (unsigned short*)(ws + 9437184);    // 9437184 B
  float* proj           = (float*)(ws);                       // aliases xn+qb (dead by then)
  unsigned short* aoutb = (unsigned short*)(ws + 18874368);   // 9437184 B
  float* musig          = (float*)(ws + 18874368);            // aliases aoutb (dead after gemm1)
  unsigned short* kb    = (unsigned short*)(ws + 28311552);   // 1245184 B
  unsigned short* vtb   = (unsigned short*)(ws + 29556736);   // 1245184 B
  unsigned short* WqT   = (unsigned short*)(ws + 30801920);   // 524288 B
  unsigned short* WkvT  = (unsigned short*)(ws + 31326208);   // 131072 B
  unsigned short* WctxT = (unsigned short*)(ws + 31457280);   // 196608 B
  unsigned short* WoutT = (unsigned short*)(ws + 31653888);   // 524288 B

  k_prep<<<dim3(2688), dim3(256), 0, stream>>>(Wq, Wkv, Wctx, Wout, WqT, WkvT, WctxT, WoutT);
  k_ln1<<<dim3(72, 4), dim3(256), 0, stream>>>(x, ngamma, xn);
  k_ctx<<<dim3(128, 4), dim3(128), 0, stream>>>(context, clng, clnb, WctxT, bctx, null_kv, kb, vtb);
  k_gemm<0><<<dim3(72, 5), dim3(256), 0, stream>>>(xn, WqT, WkvT, qb, kb, vtb, nullptr);
  k_attn<<<dim3(72, 8, 4), dim3(256), 0, stream>>>(qb, kb, vtb, aoutb);
  k_gemm<1><<<dim3(72, 4), dim3(256), 0, stream>>>(aoutb, WoutT, nullptr, nullptr, nullptr, nullptr, proj);
  k_stats<<<dim3(2304), dim3(256), 0, stream>>>(proj, musig);
  k_final2<<<dim3(72, 8, 4), dim3(256), 0, stream>>>(proj, musig, olng, x, y);
}

// Round 5
// 213.604 us; speedup vs baseline: 1.8541x; 1.8541x over previous
//
#include <hip/hip_runtime.h>

typedef __attribute__((ext_vector_type(8))) short bf16x8;
typedef __attribute__((ext_vector_type(4))) float f32x4;

#define LPAD 2432
#define LKV  2382
#define NSEQ 2304
#define CDIM 512

__device__ __forceinline__ unsigned short f2bf(float f) {
  unsigned int u = __builtin_bit_cast(unsigned int, f);
  u += 0x7fffu + ((u >> 16) & 1u);
  return (unsigned short)(u >> 16);
}
__device__ __forceinline__ float bf2f(unsigned short s) {
  unsigned int u = ((unsigned int)s) << 16;
  return __builtin_bit_cast(float, u);
}
__device__ __forceinline__ f32x4 MFMA(bf16x8 a, bf16x8 b, f32x4 c) {
  return __builtin_amdgcn_mfma_f32_16x16x32_bf16(a, b, c, 0, 0, 0);
}
__device__ __forceinline__ void stage16(const unsigned short* g, unsigned short* l) {
  __builtin_amdgcn_global_load_lds((const __attribute__((address_space(1))) void*)g,
                                   (__attribute__((address_space(3))) void*)l, 16, 0, 0);
}

// ---------------- weight transpose + bf16 convert ----------------
__global__ void k_prep(const float* __restrict__ Wq, const float* __restrict__ Wkv,
                       const float* __restrict__ Wctx, const float* __restrict__ Wout,
                       unsigned short* __restrict__ WqT, unsigned short* __restrict__ WkvT,
                       unsigned short* __restrict__ WctxT, unsigned short* __restrict__ WoutT) {
  int idx = blockIdx.x * 256 + threadIdx.x;
  if (idx < 262144) {
    int n = idx >> 9, k = idx & 511;
    WqT[idx] = f2bf(Wq[k * 512 + n]);
  } else if ((idx -= 262144) < 65536) {
    int n = idx >> 9, k = idx & 511;
    WkvT[idx] = f2bf(Wkv[k * 128 + n]);
  } else if ((idx -= 65536) < 98304) {
    int n = idx / 768, k = idx - n * 768;
    WctxT[idx] = f2bf(Wctx[k * 128 + n]);
  } else {
    idx -= 98304;
    int n = idx >> 9, k = idx & 511;
    WoutT[idx] = f2bf(Wout[k * 512 + n]);
  }
}

// ---------------- LN over C of x (B,C,N) -> xn bf16 (B*N, C) ----------------
__global__ void k_ln1(const float* __restrict__ x, const float* __restrict__ g,
                      unsigned short* __restrict__ xn) {
  int b = blockIdx.y;
  int i0 = blockIdx.x * 32;
  int t = threadIdx.x;
  int ii = t & 31, ci = t >> 5;
  const float* xb = x + (size_t)b * CDIM * NSEQ;
  float s = 0.f, s2 = 0.f;
  for (int c = ci; c < CDIM; c += 8) {
    float v = xb[(size_t)c * NSEQ + i0 + ii];
    s += v; s2 += v * v;
  }
  __shared__ float ls[8][32], ls2[8][32];
  __shared__ float lmu[32], lrs[32];
  ls[ci][ii] = s; ls2[ci][ii] = s2;
  __syncthreads();
  if (t < 32) {
    float a = 0.f, a2 = 0.f;
    for (int q = 0; q < 8; q++) { a += ls[q][t]; a2 += ls2[q][t]; }
    float mu = a * (1.0f / 512.0f);
    float var = a2 * (1.0f / 512.0f) - mu * mu;
    lmu[t] = mu; lrs[t] = rsqrtf(var + 1e-5f);
  }
  __syncthreads();
  float mu = lmu[ii], rs = lrs[ii];
  unsigned short* xrow = xn + (size_t)(b * NSEQ + i0 + ii) * CDIM;
  for (int c = ci; c < CDIM; c += 8) {
    float v = xb[(size_t)c * NSEQ + i0 + ii];
    xrow[c] = f2bf((v - mu) * rs * g[c]);
  }
}

// ---------------- context LN + projection; null row + zero pads ----------
__global__ void k_ctx(const float* __restrict__ ctx, const float* __restrict__ g,
                      const float* __restrict__ be, const unsigned short* __restrict__ WctxT,
                      const float* __restrict__ bctx, const float* __restrict__ null_kv,
                      unsigned short* __restrict__ kb, unsigned short* __restrict__ vt) {
  int b = blockIdx.y, j = blockIdx.x;
  int t = threadIdx.x;
  if (j == 77) {
    if (t < 64) kb[((size_t)b * LPAD + 77) * 64 + t] = f2bf(null_kv[t]);
    else vt[((size_t)b * 64 + (t - 64)) * LPAD + 77] = f2bf(null_kv[64 + (t - 64)]);
    return;
  }
  if (j > 77) {
    int jj = LKV + (j - 78);
    if (t < 64) kb[((size_t)b * LPAD + jj) * 64 + t] = 0;
    else vt[((size_t)b * 64 + (t - 64)) * LPAD + jj] = 0;
    return;
  }
  __shared__ float row[768];
  __shared__ float red[4];
  const float* src = ctx + (size_t)(b * 77 + j) * 768;
  float s = 0.f, s2 = 0.f;
  for (int k = t; k < 768; k += 128) {
    float v = src[k];
    row[k] = v; s += v; s2 += v * v;
  }
  for (int o = 32; o; o >>= 1) { s += __shfl_xor(s, o); s2 += __shfl_xor(s2, o); }
  if ((t & 63) == 0) { red[(t >> 6) * 2] = s; red[(t >> 6) * 2 + 1] = s2; }
  __syncthreads();
  float S = red[0] + red[2], S2 = red[1] + red[3];
  float mu = S * (1.0f / 768.0f);
  float rs = rsqrtf(S2 * (1.0f / 768.0f) - mu * mu + 1e-5f);
  __syncthreads();
  for (int k = t; k < 768; k += 128) row[k] = (row[k] - mu) * rs * g[k] + be[k];
  __syncthreads();
  const uint4* w4 = reinterpret_cast<const uint4*>(WctxT + (size_t)t * 768);
  float acc = 0.f;
  for (int k8 = 0; k8 < 96; k8++) {
    union { uint4 u; unsigned short s[8]; } wv;
    wv.u = w4[k8];
#pragma unroll
    for (int e = 0; e < 8; e++) acc += row[k8 * 8 + e] * bf2f(wv.s[e]);
  }
  acc += bctx[t];
  if (t < 64) kb[((size_t)b * LPAD + j) * 64 + t] = f2bf(acc);
  else vt[((size_t)b * 64 + (t - 64)) * LPAD + j] = f2bf(acc);
}

// ---------------- MFMA GEMM ----------------
template <int MODE>
__global__ __launch_bounds__(256, 1) void k_gemm(
    const unsigned short* __restrict__ A, const unsigned short* __restrict__ BT0,
    const unsigned short* __restrict__ BT1, unsigned short* __restrict__ out_q,
    unsigned short* __restrict__ out_k, unsigned short* __restrict__ out_vt,
    float* __restrict__ out_proj) {
  int m0 = blockIdx.x * 128, n0 = blockIdx.y * 128;
  int t = threadIdx.x;
  int lane = t & 63, w = t >> 6;
  int wm = w >> 1, wn = w & 1;
  int G = lane >> 4, li = lane & 15;
  __shared__ unsigned short Al[128][72];
  __shared__ unsigned short Bl[128][72];
  const unsigned short* BT = (MODE == 0 && n0 >= 512) ? BT1 : BT0;
  int bn0 = (MODE == 0 && n0 >= 512) ? n0 - 512 : n0;
  f32x4 zero = {0.f, 0.f, 0.f, 0.f};
  f32x4 acc[4][4];
#pragma unroll
  for (int a = 0; a < 4; a++)
#pragma unroll
    for (int c = 0; c < 4; c++) acc[a][c] = zero;
  int sr = t >> 1, sc = (t & 1) * 32;
  for (int k0 = 0; k0 < 512; k0 += 64) {
    const uint4* sA = reinterpret_cast<const uint4*>(A + (size_t)(m0 + sr) * 512 + k0 + sc);
    const uint4* sB = reinterpret_cast<const uint4*>(BT + (size_t)(bn0 + sr) * 512 + k0 + sc);
    uint4 a0 = sA[0], a1 = sA[1], a2 = sA[2], a3 = sA[3];
    uint4 b0 = sB[0], b1 = sB[1], b2 = sB[2], b3 = sB[3];
    uint4* dA = reinterpret_cast<uint4*>(&Al[sr][sc]);
    uint4* dB = reinterpret_cast<uint4*>(&Bl[sr][sc]);
    dA[0] = a0; dA[1] = a1; dA[2] = a2; dA[3] = a3;
    dB[0] = b0; dB[1] = b1; dB[2] = b2; dB[3] = b3;
    __syncthreads();
#pragma unroll
    for (int ks = 0; ks < 2; ks++) {
      bf16x8 af[4], bfr[4];
#pragma unroll
      for (int f = 0; f < 4; f++) {
        af[f] = *reinterpret_cast<const bf16x8*>(&Al[wm * 64 + f * 16 + li][ks * 32 + G * 8]);
        bfr[f] = *reinterpret_cast<const bf16x8*>(&Bl[wn * 64 + f * 16 + li][ks * 32 + G * 8]);
      }
#pragma unroll
      for (int fm = 0; fm < 4; fm++)
#pragma unroll
        for (int fn = 0; fn < 4; fn++)
          acc[fm][fn] = MFMA(af[fm], bfr[fn], acc[fm][fn]);
    }
    __syncthreads();
  }
#pragma unroll
  for (int fm = 0; fm < 4; fm++)
#pragma unroll
    for (int fn = 0; fn < 4; fn++)
#pragma unroll
      for (int r = 0; r < 4; r++) {
        int row = m0 + wm * 64 + fm * 16 + G * 4 + r;
        int col = n0 + wn * 64 + fn * 16 + li;
        float v = acc[fm][fn][r];
        if (MODE == 0) {
          int b = row / NSEQ, i = row - b * NSEQ;
          if (col < 512) out_q[(size_t)row * 512 + col] = f2bf(v * 0.125f);
          else if (col < 576) out_k[((size_t)b * LPAD + 78 + i) * 64 + (col - 512)] = f2bf(v);
          else out_vt[((size_t)b * 64 + (col - 576)) * LPAD + (78 + i)] = f2bf(v);
        } else {
          out_proj[(size_t)row * 512 + col] = v;
        }
      }
}

// ---------------- flash attention: 4 waves = 4 heads, LDS-staged K/V --------
// K tile [64 j][64 d], V^T tile [64 d][64 j] staged via global_load_lds with
// source-side XOR swizzle (granule16 col ^= row&7); LDS linear; reads apply
// the same XOR -> conflict-free. One barrier per tile (drains vmcnt + reuse).
__global__ __launch_bounds__(256, 2) void k_attn(
    const unsigned short* __restrict__ q, const unsigned short* __restrict__ kbuf,
    const unsigned short* __restrict__ vt, unsigned short* __restrict__ aout) {
  int it = blockIdx.x, hh = blockIdx.y, b = blockIdx.z;
  int i0 = it * 32;
  int t = threadIdx.x;
  int w = t >> 6, lane = t & 63;
  int G = lane >> 4, li = lane & 15, li7 = lane & 7;
  int h = hh * 4 + w;

  __shared__ __align__(16) unsigned short Kl[2][4096];
  __shared__ __align__(16) unsigned short Vl[2][4096];

  // staging geometry: flat granule p covers row p>>3, swizzled col16 (p&7)^(row&7)
  int r1 = t >> 3;
  int c1 = ((t & 7) ^ (r1 & 7)) * 8;

  const unsigned short* kbase = kbuf + (size_t)b * LPAD * 64;
  const unsigned short* vbase = vt + (size_t)b * 64 * LPAD;

  bf16x8 qf[2][2];
#pragma unroll
  for (int fi = 0; fi < 2; fi++)
#pragma unroll
    for (int ks = 0; ks < 2; ks++)
      qf[fi][ks] = *reinterpret_cast<const bf16x8*>(
          q + (size_t)(b * NSEQ + i0 + fi * 16 + li) * CDIM + h * 64 + ks * 32 + G * 8);

  // stage tile 0
  stage16(kbase + (size_t)r1 * 64 + c1, &Kl[0][w * 512]);
  stage16(kbase + (size_t)(r1 + 32) * 64 + c1, &Kl[0][2048 + w * 512]);
  stage16(vbase + (size_t)r1 * LPAD + c1, &Vl[0][w * 512]);
  stage16(vbase + (size_t)(r1 + 32) * LPAD + c1, &Vl[0][2048 + w * 512]);

  f32x4 zero = {0.f, 0.f, 0.f, 0.f};
  f32x4 OT[4][2];  // [fd][fi]; row d = fd*16+G*4+r, col i = fi*16+li
#pragma unroll
  for (int fd = 0; fd < 4; fd++)
#pragma unroll
    for (int fi = 0; fi < 2; fi++) OT[fd][fi] = zero;
  float m_[2] = {-1e30f, -1e30f};
  float l_[2] = {0.f, 0.f};

  __syncthreads();

  for (int jt = 0; jt < 38; jt++) {
    int cur = jt & 1, nxt = cur ^ 1;
    int j0 = jt * 64;
    if (jt < 37) {
      int j1 = j0 + 64;
      stage16(kbase + (size_t)(j1 + r1) * 64 + c1, &Kl[nxt][w * 512]);
      stage16(kbase + (size_t)(j1 + r1 + 32) * 64 + c1, &Kl[nxt][2048 + w * 512]);
      stage16(vbase + (size_t)r1 * LPAD + j1 + c1, &Vl[nxt][w * 512]);
      stage16(vbase + (size_t)(r1 + 32) * LPAD + j1 + c1, &Vl[nxt][2048 + w * 512]);
    }
    const char* Kc = (const char*)Kl[cur];
    const char* Vc = (const char*)Vl[cur];

    f32x4 S[4][2];
#pragma unroll
    for (int fj = 0; fj < 4; fj++) { S[fj][0] = zero; S[fj][1] = zero; }
#pragma unroll
    for (int ks = 0; ks < 2; ks++) {
      bf16x8 kf[4];
#pragma unroll
      for (int fj = 0; fj < 4; fj++)
        kf[fj] = *reinterpret_cast<const bf16x8*>(
            Kc + ((((fj * 16 + li) * 8) + ((ks * 4 + G) ^ li7)) << 4));
#pragma unroll
      for (int fj = 0; fj < 4; fj++)
#pragma unroll
        for (int fi = 0; fi < 2; fi++)
          S[fj][fi] = MFMA(kf[fj], qf[fi][ks], S[fj][fi]);
    }
    if (j0 + 64 > LKV) {
#pragma unroll
      for (int fj = 0; fj < 4; fj++)
#pragma unroll
        for (int r = 0; r < 4; r++) {
          int jg = j0 + fj * 16 + G * 4 + r;
          if (jg >= LKV) { S[fj][0][r] = -1e30f; S[fj][1][r] = -1e30f; }
        }
    }
    // softmax (stats per lane li = q-row), immediate bf16 pack
    bf16x8 pf[2][2];
#pragma unroll
    for (int fi = 0; fi < 2; fi++) {
      float tm = -1e30f;
#pragma unroll
      for (int fj = 0; fj < 4; fj++)
#pragma unroll
        for (int r = 0; r < 4; r++) tm = fmaxf(tm, S[fj][fi][r]);
      tm = fmaxf(tm, __shfl_xor(tm, 16));
      tm = fmaxf(tm, __shfl_xor(tm, 32));
      float mn = fmaxf(m_[fi], tm);
      float alpha = __expf(m_[fi] - mn);
      float e[4][4];
      float ts = 0.f;
#pragma unroll
      for (int fj = 0; fj < 4; fj++)
#pragma unroll
        for (int r = 0; r < 4; r++) {
          float ev = __expf(S[fj][fi][r] - mn);
          e[fj][r] = ev;
          ts += ev;
        }
      ts += __shfl_xor(ts, 16);
      ts += __shfl_xor(ts, 32);
      l_[fi] = l_[fi] * alpha + ts;
      m_[fi] = mn;
#pragma unroll
      for (int ks = 0; ks < 2; ks++) {
        union { unsigned short s[8]; bf16x8 v; } u;
#pragma unroll
        for (int s8 = 0; s8 < 8; s8++) u.s[s8] = f2bf(e[2 * ks + (s8 >> 2)][s8 & 3]);
        pf[fi][ks] = u.v;
      }
#pragma unroll
      for (int fd = 0; fd < 4; fd++)
#pragma unroll
        for (int r = 0; r < 4; r++) OT[fd][fi][r] *= alpha;
    }
    // PV from LDS V^T: rows d=fd*16+li, cols j via same k-bijection as pf
#pragma unroll
    for (int ks = 0; ks < 2; ks++) {
#pragma unroll
      for (int fd = 0; fd < 4; fd++) {
        const char* vr = Vc + (size_t)(fd * 16 + li) * 128 + ((G & 1) << 3);
        union { unsigned short s[8]; uint2 u2[2]; bf16x8 v; } uv;
        uv.u2[0] = *reinterpret_cast<const uint2*>(vr + ((((ks * 4) + (G >> 1)) ^ li7) << 4));
        uv.u2[1] = *reinterpret_cast<const uint2*>(vr + ((((ks * 4) + (G >> 1) + 2) ^ li7) << 4));
#pragma unroll
        for (int fi = 0; fi < 2; fi++) OT[fd][fi] = MFMA(uv.v, pf[fi][ks], OT[fd][fi]);
      }
    }
    __syncthreads();
  }

#pragma unroll
  for (int fi = 0; fi < 2; fi++) {
    float inv = 1.0f / l_[fi];
#pragma unroll
    for (int fd = 0; fd < 4; fd++) {
      union { unsigned short us[4]; uint2 u2; } pk;
#pragma unroll
      for (int r = 0; r < 4; r++) pk.us[r] = f2bf(OT[fd][fi][r] * inv);
      *reinterpret_cast<uint2*>(
          aout + (size_t)(b * NSEQ + i0 + fi * 16 + li) * CDIM + h * 64 + fd * 16 + G * 4) =
          pk.u2;
    }
  }
}

// ---------------- per-row LN stats of proj (coalesced) ----------------
__global__ void k_stats(const float* __restrict__ proj, float* __restrict__ musig) {
  int w = threadIdx.x >> 6, lane = threadIdx.x & 63;
  int row = blockIdx.x * 4 + w;
  const float* pr = proj + (size_t)row * CDIM;
  const float4* p4 = reinterpret_cast<const float4*>(pr + lane * 8);
  float4 a = p4[0], bq = p4[1];
  float s = a.x + a.y + a.z + a.w + bq.x + bq.y + bq.z + bq.w;
  float s2 = a.x * a.x + a.y * a.y + a.z * a.z + a.w * a.w +
             bq.x * bq.x + bq.y * bq.y + bq.z * bq.z + bq.w * bq.w;
  for (int o = 32; o; o >>= 1) { s += __shfl_xor(s, o); s2 += __shfl_xor(s2, o); }
  if (lane == 0) {
    float mu = s * (1.0f / 512.0f);
    float var = s2 * (1.0f / 512.0f) - mu * mu;
    musig[row] = mu;
    musig[4 * NSEQ + row] = rsqrtf(var + 1e-5f);
  }
}

// ---------------- final LN + residual, LDS-transposed, fully coalesced ------
__global__ void k_final2(const float* __restrict__ proj, const float* __restrict__ musig,
                         const float* __restrict__ g, const float* __restrict__ x,
                         float* __restrict__ y) {
  int i0 = blockIdx.x * 32, c0 = blockIdx.y * 64, b = blockIdx.z;
  int t = threadIdx.x;
  __shared__ float lds[32][65];
  {
    int il = t >> 3, cB = (t & 7) * 8;
    const float4* src = reinterpret_cast<const float4*>(
        proj + (size_t)(b * NSEQ + i0 + il) * CDIM + c0 + cB);
    float4 v0 = src[0], v1 = src[1];
    *reinterpret_cast<float4*>(&lds[il][cB]) = v0;
    *reinterpret_cast<float4*>(&lds[il][cB + 4]) = v1;
  }
  __syncthreads();
  int ii = t & 31, cg = t >> 5;
  float mu = musig[b * NSEQ + i0 + ii];
  float rs = musig[4 * NSEQ + b * NSEQ + i0 + ii];
  const float* xb = x + (size_t)b * CDIM * NSEQ;
  float* yb = y + (size_t)b * CDIM * NSEQ;
#pragma unroll
  for (int cc = 0; cc < 8; cc++) {
    int cl = cg * 8 + cc;
    int c = c0 + cl;
    float v = lds[ii][cl];
    yb[(size_t)c * NSEQ + i0 + ii] = xb[(size_t)c * NSEQ + i0 + ii] + (v - mu) * rs * g[c];
  }
}

extern "C" void kernel_launch(void* const* d_in, const int* in_sizes, int n_in,
                              void* d_out, int out_size, void* d_ws, size_t ws_size,
                              hipStream_t stream) {
  const float* x       = (const float*)d_in[0];
  const float* context = (const float*)d_in[1];
  const float* ngamma  = (const float*)d_in[2];
  const float* null_kv = (const float*)d_in[3];
  const float* Wq      = (const float*)d_in[4];
  const float* Wkv     = (const float*)d_in[5];
  const float* clng    = (const float*)d_in[6];
  const float* clnb    = (const float*)d_in[7];
  const float* Wctx    = (const float*)d_in[8];
  const float* bctx    = (const float*)d_in[9];
  const float* Wout    = (const float*)d_in[10];
  const float* olng    = (const float*)d_in[11];
  float* y = (float*)d_out;
  char* ws = (char*)d_ws;

  unsigned short* xn    = (unsigned short*)(ws);              // 9437184 B
  unsigned short* qb    = (unsigned short*)(ws + 9437184);    // 9437184 B
  float* proj           = (float*)(ws);                       // aliases xn+qb (dead by then)
  unsigned short* aoutb = (unsigned short*)(ws + 18874368);   // 9437184 B
  float* musig          = (float*)(ws + 18874368);            // aliases aoutb (dead after gemm1)
  unsigned short* kb    = (unsigned short*)(ws + 28311552);   // 1245184 B
  unsigned short* vtb   = (unsigned short*)(ws + 29556736);   // 1245184 B
  unsigned short* WqT   = (unsigned short*)(ws + 30801920);   // 524288 B
  unsigned short* WkvT  = (unsigned short*)(ws + 31326208);   // 131072 B
  unsigned short* WctxT = (unsigned short*)(ws + 31457280);   // 196608 B
  unsigned short* WoutT = (unsigned short*)(ws + 31653888);   // 524288 B

  k_prep<<<dim3(2688), dim3(256), 0, stream>>>(Wq, Wkv, Wctx, Wout, WqT, WkvT, WctxT, WoutT);
  k_ln1<<<dim3(72, 4), dim3(256), 0, stream>>>(x, ngamma, xn);
  k_ctx<<<dim3(128, 4), dim3(128), 0, stream>>>(context, clng, clnb, WctxT, bctx, null_kv, kb, vtb);
  k_gemm<0><<<dim3(72, 5), dim3(256), 0, stream>>>(xn, WqT, WkvT, qb, kb, vtb, nullptr);
  k_attn<<<dim3(72, 2, 4), dim3(256), 0, stream>>>(qb, kb, vtb, aoutb);
  k_gemm<1><<<dim3(72, 4), dim3(256), 0, stream>>>(aoutb, WoutT, nullptr, nullptr, nullptr, nullptr, proj);
  k_stats<<<dim3(2304), dim3(256), 0, stream>>>(proj, musig);
  k_final2<<<dim3(72, 8, 4), dim3(256), 0, stream>>>(proj, musig, olng, x, y);
}